// Round 1
// 470.255 us; speedup vs baseline: 1.1863x; 1.1863x over previous
//
#include <hip/hip_runtime.h>
#include <cstdint>

typedef unsigned short u16;
typedef __bf16 bf16x8 __attribute__((ext_vector_type(8)));
typedef float f32x4 __attribute__((ext_vector_type(4)));
typedef int   i32x4 __attribute__((ext_vector_type(4)));
typedef u16   u16x4 __attribute__((ext_vector_type(4)));

#define M_DIM 8192   // B*S = 4*2048
#define N_DIM 4096   // UNITS
#define K_DIM 4096   // D

#define GLOBAL_AS(p) ((const __attribute__((address_space(1))) void*)(p))
#define LDS_AS(p)    ((__attribute__((address_space(3))) void*)(p))

// ---------- fp32 -> bf16 bits, round-to-nearest-even ----------
__device__ __forceinline__ u16 f2bf(float f) {
    union { float f; uint32_t u; } x; x.f = f;
    uint32_t u = x.u;
    uint32_t r = (u + 0x7fffu + ((u >> 16) & 1u)) >> 16;
    return (u16)r;
}

// ---------- fused prepass: unchanged (W-transpose + X-convert) ----------
__global__ __launch_bounds__(256) void prepass_kernel(const float* __restrict__ X,
                                                      const int* __restrict__ W,
                                                      u16* __restrict__ Xb,
                                                      u16* __restrict__ Wt) {
    const int bid = blockIdx.x;
    const int t   = threadIdx.x;
    if (bid < 4096) {
        __shared__ int tile[64][65];
        const int n0 = (bid & 63) * 64;
        const int k0 = (bid >> 6) * 64;
#pragma unroll
        for (int i = 0; i < 4; i++) {
            int e = t + i * 256;
            int r = e >> 4;
            int c = (e & 15) * 4;
            i32x4 v = __builtin_nontemporal_load(
                (const i32x4*)(W + (size_t)(k0 + r) * N_DIM + n0 + c));
            tile[r][c] = v.x; tile[r][c + 1] = v.y; tile[r][c + 2] = v.z; tile[r][c + 3] = v.w;
        }
        __syncthreads();
        {
            int n = t >> 2, ks = (t & 3) * 16;
            __align__(16) u16 o[16];
#pragma unroll
            for (int i = 0; i < 16; i++)
                o[i] = f2bf((float)tile[ks + i][n]);
            u16* dst = Wt + (size_t)(n0 + n) * K_DIM + k0 + ks;
            *(uint4*)(dst)     = *(const uint4*)&o[0];
            *(uint4*)(dst + 8) = *(const uint4*)&o[8];
        }
    } else {
        const size_t base = (size_t)(bid - 4096) * 4096;
        const f32x4*   x4 = (const f32x4*)X;
        u16x4*         o4 = (u16x4*)Xb;
#pragma unroll
        for (int it = 0; it < 8; it++) {
            size_t ia = base + (size_t)it * 512 + t;
            size_t ib = ia + 256;
            f32x4 a = __builtin_nontemporal_load(x4 + ia);
            f32x4 b = __builtin_nontemporal_load(x4 + ib);
            u16x4 oa, ob;
            oa.x = f2bf(a.x); oa.y = f2bf(a.y); oa.z = f2bf(a.z); oa.w = f2bf(a.w);
            ob.x = f2bf(b.x); ob.y = f2bf(b.y); ob.z = f2bf(b.z); ob.w = f2bf(b.w);
            o4[ia] = oa;
            o4[ib] = ob;
        }
    }
}

// =====================================================================
// 256x256 8-phase GEMM (m201 template, plain HIP):
//  - BK=64, 512 threads = 8 waves (2 M x 4 N), per-wave C = 128x64
//  - LDS 128 KiB: A[2buf][256][64] bf16 @ 0, B[2buf][256][64] @ 64KiB
//  - T2: chunk-XOR swizzle (chunk ^= row&7) applied on the READ side and
//    pre-applied to the GLOBAL source of global_load_lds (LDS dest linear)
//  - T3/T4: 4 phases per K-tile (one 128x128 C quadrant each), 1 half-tile
//    staged per phase, raw s_barrier (no vmcnt(0) drain), steady-state
//    s_waitcnt vmcnt(6) once per K-tile (3 half-tiles in flight)
//  - T5: setprio(1) around each 16-MFMA cluster
//  - T1: bijective XCD swizzle on the 512-block grid (512 % 8 == 0)
// Fragment reuse keeps LDS traffic at the minimum 24 ds_read_b128/wave/tile:
//   ph1: read A-set0(8) + B-set0(4), MFMA Q(0,0)
//   ph2: read B-set1(4),             MFMA Q(0,1)   (A-set0 reused from regs)
//   ph3: read A-set1(8),             MFMA Q(1,0)   (B-set0 reused from regs)
//   ph4: no reads,                   MFMA Q(1,1)   (A-set1, B-set1 from regs)
// Stage schedule (region's last reader is barrier-separated from the issue):
//   ph1: A_hi(T+1)   ph2: A_lo(T+2)   ph3: B_lo(T+2)   ph4: B_hi(T+2)
// =====================================================================

#define BK 64
#define NT (K_DIM / BK)
static_assert(NT >= 4 && (NT & 1) == 0, "tile count must be even and >= 4");

#define BARRIER() do { asm volatile("" ::: "memory"); \
                       __builtin_amdgcn_s_barrier();  \
                       asm volatile("" ::: "memory"); } while (0)
#define WAIT_LGKM() asm volatile("s_waitcnt lgkmcnt(0)" ::: "memory")
#define VMCNT(n)    asm volatile("s_waitcnt vmcnt(" #n ")" ::: "memory")

// read 4 m-frags x 2 k-steps (8 x ds_read_b128), swizzled
#define READ_A(dst, mhv)                                                          \
    _Pragma("unroll") for (int i = 0; i < 4; i++) {                               \
        const char* p_ = As_ + ((mhv) * 128 + wrow * 64 + i * 16 + fr) * 128;     \
        _Pragma("unroll") for (int kk = 0; kk < 2; kk++)                          \
            dst[i][kk] = *(const bf16x8*)(p_ + ((kk * 64 + fk2) ^ sw));           \
    }

// read 2 n-frags x 2 k-steps (4 x ds_read_b128), swizzled
#define READ_B(dst, nhv)                                                          \
    _Pragma("unroll") for (int j = 0; j < 2; j++) {                               \
        const char* p_ = Bs_ + ((nhv) * 128 + wcol * 32 + j * 16 + fr) * 128;     \
        _Pragma("unroll") for (int kk = 0; kk < 2; kk++)                          \
            dst[j][kk] = *(const bf16x8*)(p_ + ((kk * 64 + fk2) ^ sw));           \
    }

#define MFMA_Q(MH, NH, aarr, barr)                                                \
    do {                                                                          \
        __builtin_amdgcn_s_setprio(1);                                            \
        _Pragma("unroll") for (int kk = 0; kk < 2; kk++)                          \
            _Pragma("unroll") for (int i = 0; i < 4; i++)                         \
                _Pragma("unroll") for (int j = 0; j < 2; j++)                     \
                    acc[MH][NH][i][j] = __builtin_amdgcn_mfma_f32_16x16x32_bf16(  \
                        aarr[i][kk], barr[j][kk], acc[MH][NH][i][j], 0, 0, 0);    \
        __builtin_amdgcn_s_setprio(0);                                            \
    } while (0)

// stage one half-tile (128 rows x 64 cols bf16 = 16 KiB) = 2 x global_load_lds
// LDS dest is linear (wave-uniform base + lane*16); the swizzle permutation is
// pre-applied to the per-lane GLOBAL address (aoffN encodes chunk^=(row&7)).
#define STAGE_A(bufv, h, kt)                                                      \
    do {                                                                          \
        const u16* g_ = gA + (size_t)(h) * (128 * K_DIM) + (kt) * 64;             \
        char* l_ = (char*)lds + (bufv) * 32768 + (h) * 16384 + wv * 1024;         \
        __builtin_amdgcn_global_load_lds(GLOBAL_AS(g_ + aoff0), LDS_AS(l_), 16, 0, 0);        \
        __builtin_amdgcn_global_load_lds(GLOBAL_AS(g_ + aoff1), LDS_AS(l_ + 8192), 16, 0, 0); \
    } while (0)

#define STAGE_B(bufv, h, kt)                                                      \
    do {                                                                          \
        const u16* g_ = gB + (size_t)(h) * (128 * K_DIM) + (kt) * 64;             \
        char* l_ = (char*)lds + 65536 + (bufv) * 32768 + (h) * 16384 + wv * 1024; \
        __builtin_amdgcn_global_load_lds(GLOBAL_AS(g_ + aoff0), LDS_AS(l_), 16, 0, 0);        \
        __builtin_amdgcn_global_load_lds(GLOBAL_AS(g_ + aoff1), LDS_AS(l_ + 8192), 16, 0, 0); \
    } while (0)

// one K-tile = 4 phases; S1..S4 are the per-phase stage statements, SYNC the
// per-tile counted vmcnt (placed after the last MFMA, before the tile barrier)
#define TILE(bv, S1, S2, S3, S4, SYNC)                                            \
    {                                                                             \
        const char* As_ = (const char*)lds + (bv) * 32768;                        \
        const char* Bs_ = (const char*)lds + 65536 + (bv) * 32768;                \
        bf16x8 a0[4][2], a1[4][2], b0[2][2], b1[2][2];                            \
        /* ph1 */                                                                 \
        READ_A(a0, 0); READ_B(b0, 0);                                             \
        S1;                                                                       \
        BARRIER(); WAIT_LGKM();                                                   \
        MFMA_Q(0, 0, a0, b0);                                                     \
        BARRIER();                                                                \
        /* ph2 */                                                                 \
        READ_B(b1, 1);                                                            \
        S2;                                                                       \
        BARRIER(); WAIT_LGKM();                                                   \
        MFMA_Q(0, 1, a0, b1);                                                     \
        BARRIER();                                                                \
        /* ph3 */                                                                 \
        READ_A(a1, 1);                                                            \
        S3;                                                                       \
        BARRIER(); WAIT_LGKM();                                                   \
        MFMA_Q(1, 0, a1, b0);                                                     \
        BARRIER();                                                                \
        /* ph4 */                                                                 \
        S4;                                                                       \
        BARRIER();                                                                \
        MFMA_Q(1, 1, a1, b1);                                                     \
        SYNC;                                                                     \
        BARRIER();                                                                \
    }

__global__ __launch_bounds__(512, 2) void gemm_bf16_kernel(const u16* __restrict__ A,
                                                           const u16* __restrict__ Bt,
                                                           const float* __restrict__ scale_p,
                                                           float* __restrict__ C) {
    __shared__ __align__(16) u16 lds[65536];   // 128 KiB: A[2][256][64] | B[2][256][64]

    const int tid  = threadIdx.x;
    const int lane = tid & 63;
    const int wv   = tid >> 6;       // wave 0..7
    const int wrow = wv >> 2;        // 0..1  (M)
    const int wcol = wv & 3;         // 0..3  (N)

    // T1: bijective XCD swizzle, 512 blocks, 8 XCDs -> 64 blocks per XCD chunk
    const int bid = blockIdx.x;
    const int wg  = ((bid & 7) << 6) | (bid >> 3);
    const size_t m0 = (size_t)(wg >> 4) * 256;   // 32 M-tiles
    const size_t n0 = (size_t)(wg & 15) * 256;   // 16 N-tiles

    // fragment addressing: row r has swizzle XOR (r&7)<<4; since every frag row
    // = multiple-of-16 + (lane&15), the XOR is the per-lane constant sw.
    const int fr  = lane & 15;
    const int fk2 = (lane >> 4) * 16;            // k byte offset {0,16,32,48}
    const int sw  = (lane & 7) << 4;

    // staging: half-tile chunk q in {tid, tid+512}; row = q>>3,
    // global chunk = (q&7) ^ (row&7)  (inverse swizzle on the source side)
    const int q0 = tid,       r0 = q0 >> 3, c0 = (q0 & 7) ^ (r0 & 7);
    const int q1 = tid + 512, r1 = q1 >> 3, c1 = (q1 & 7) ^ (r1 & 7);
    const size_t aoff0 = (size_t)r0 * K_DIM + c0 * 8;
    const size_t aoff1 = (size_t)r1 * K_DIM + c1 * 8;

    const u16* gA = A  + m0 * K_DIM;
    const u16* gB = Bt + n0 * K_DIM;

    f32x4 acc[2][2][4][2] = {};

    // prologue: tile 0 complete (4 halves) + A_lo,B_lo,B_hi of tile 1 = 7 halves
    STAGE_A(0, 0, 0);   // A_lo(0)
    STAGE_B(0, 0, 0);   // B_lo(0)
    STAGE_B(0, 1, 0);   // B_hi(0)
    STAGE_A(0, 1, 0);   // A_hi(0)
    STAGE_A(1, 0, 1);   // A_lo(1)
    STAGE_B(1, 0, 1);   // B_lo(1)
    STAGE_B(1, 1, 1);   // B_hi(1)
    VMCNT(6);           // tile 0 landed; 3 half-tiles of tile 1 in flight
    BARRIER();

#pragma unroll 2
    for (int T = 0; T < NT - 2; ++T) {
        const int b  = T & 1;
        const int bo = b ^ 1;
        TILE(b,
             STAGE_A(bo, 1, T + 1),    // A_hi(T+1): completes tile T+1 staging
             STAGE_A(b,  0, T + 2),    // A_lo(T+2): region freed end of ph1
             STAGE_B(b,  0, T + 2),    // B_lo(T+2): region freed end of ph1
             STAGE_B(b,  1, T + 2),    // B_hi(T+2): region freed end of ph2
             VMCNT(6));                // tile T+1 landed; 3 halves of T+2 in flight
    }
    // tile NT-2 (buf 0): only A_hi(NT-1) remains to stage; drain at the end
    TILE(0, STAGE_A(1, 1, NT - 1), , , , VMCNT(0));
    // tile NT-1 (buf 1): pure compute
    TILE(1, , , , , );

    // epilogue: D layout col = lane&15, row = (lane>>4)*4 + reg; NT stores
    const float s = *scale_p;
    const int ec = lane & 15;
    const int er = (lane >> 4) * 4;
#pragma unroll
    for (int mh = 0; mh < 2; mh++)
#pragma unroll
        for (int nh = 0; nh < 2; nh++)
#pragma unroll
            for (int i = 0; i < 4; i++)
#pragma unroll
                for (int j = 0; j < 2; j++) {
                    float* cp = C + (m0 + mh * 128 + wrow * 64 + i * 16 + er) * N_DIM
                                  + (n0 + nh * 128 + wcol * 32 + j * 16 + ec);
#pragma unroll
                    for (int r = 0; r < 4; r++)
                        __builtin_nontemporal_store(acc[mh][nh][i][j][r] * s,
                                                    cp + (size_t)r * N_DIM);
                }
}

// ---------- fallback fp32 GEMM (only if ws too small; correctness net) ----------
__global__ __launch_bounds__(256) void fb_gemm_kernel(const float* __restrict__ X,
                                                      const int* __restrict__ W,
                                                      const float* __restrict__ sp,
                                                      float* __restrict__ Y) {
    __shared__ float Xs[16][64];
    __shared__ float Ws[16][64];
    const int t = threadIdx.x;
    const int tx = t & 15, ty = t >> 4;
    const int m0 = blockIdx.y * 64, n0 = blockIdx.x * 64;
    float acc[4][4] = {};
    for (int k0 = 0; k0 < K_DIM; k0 += 16) {
#pragma unroll
        for (int i = 0; i < 4; i++) {
            int e = t + i * 256;
            int r = e >> 4, c = e & 15;
            Xs[c][r] = X[(size_t)(m0 + r) * K_DIM + k0 + c];
            int rw = e >> 6, cw = e & 63;
            Ws[rw][cw] = (float)W[(size_t)(k0 + rw) * N_DIM + n0 + cw];
        }
        __syncthreads();
#pragma unroll
        for (int kk = 0; kk < 16; kk++)
#pragma unroll
            for (int i = 0; i < 4; i++)
#pragma unroll
                for (int j = 0; j < 4; j++)
                    acc[i][j] += Xs[kk][ty * 4 + i] * Ws[kk][tx * 4 + j];
        __syncthreads();
    }
    const float s = *sp;
#pragma unroll
    for (int i = 0; i < 4; i++)
#pragma unroll
        for (int j = 0; j < 4; j++)
            Y[(size_t)(m0 + ty * 4 + i) * N_DIM + n0 + tx * 4 + j] = acc[i][j] * s;
}

extern "C" void kernel_launch(void* const* d_in, const int* in_sizes, int n_in,
                              void* d_out, int out_size, void* d_ws, size_t ws_size,
                              hipStream_t stream) {
    const float* X  = (const float*)d_in[0];
    const int*   W  = (const int*)d_in[1];
    const float* sp = (const float*)d_in[2];
    float* Y = (float*)d_out;

    const size_t xb = (size_t)M_DIM * K_DIM * sizeof(u16);   // 64 MB
    const size_t wb = (size_t)N_DIM * K_DIM * sizeof(u16);   // 32 MB

    if (ws_size >= xb + wb) {
        u16* Xb = (u16*)d_ws;
        u16* Wt = (u16*)((char*)d_ws + xb);
        prepass_kernel<<<6144, 256, 0, stream>>>(X, W, Xb, Wt);
        gemm_bf16_kernel<<<512, 512, 0, stream>>>(Xb, Wt, sp, Y);
    } else {
        fb_gemm_kernel<<<dim3(N_DIM / 64, M_DIM / 64), 256, 0, stream>>>(X, W, sp, Y);
    }
}